// Round 9
// baseline (188.726 us; speedup 1.0000x reference)
//
#include <hip/hip_runtime.h>

// x[64][16][8192] f32, J=4, LEVELS=13, eps 1e-5.
// targets[j] = blockmean(2^(13-j)); inputs[j] = BN(blockmean(2^(13-j)) - blockmean(2^(14-j))), input[0]=BN(m0)
// Output [2][4][64][16][8192] f32.
// SINGLE dispatch, 1024 blocks (one per row):
//   phase 1: NT-read row -> 15 block-mean stats (regs + volatile global publish + arrive)
//   phase 2: write 4 target rows (overlaps all other blocks' phase 1)
//   phase 3: spin on arrive-counter (expected ~zero wait), acquire fence
//   phase 4: wave j computes BN(j,c) from stats table; phase 5: write 4 input rows

#define SSTR 16
// stats row: [0]=m0, [1..2]=m1, [3..6]=m2, [7..14]=m3  (level j at base (1<<j)-1, count 1<<j)

typedef float f32x4 __attribute__((ext_vector_type(4)));

__global__ __launch_bounds__(256) void fused_kernel(const float* __restrict__ x,
                                                    const float* __restrict__ gamma,
                                                    const float* __restrict__ beta,
                                                    float* __restrict__ stats,
                                                    int* __restrict__ counter,
                                                    f32x4* __restrict__ out) {
    int row = blockIdx.x;                 // 0..1023  (b=row>>4, c=row&15)
    int c = row & 15;
    int t = threadIdx.x;                  // 0..255
    int lane = t & 63, wave = t >> 6;

    // ---- phase 1: row stats ----
    const f32x4* xr = reinterpret_cast<const f32x4*>(x) + (size_t)row * 2048;
    float s[8];
#pragma unroll
    for (int k = 0; k < 8; ++k) {
        f32x4 v = __builtin_nontemporal_load(&xr[t + 256 * k]);  // iter k = 1024-block k
        s[k] = (v.x + v.y) + (v.z + v.w);
    }
    __shared__ float red[8][4];
    __shared__ float sb[16];
#pragma unroll
    for (int k = 0; k < 8; ++k) {
        float v = s[k];
#pragma unroll
        for (int off = 32; off; off >>= 1) v += __shfl_down(v, off, 64);
        if (lane == 0) red[k][wave] = v;
    }
    __syncthreads();
    if (t < 8) sb[7 + t] = (red[t][0] + red[t][1] + red[t][2] + red[t][3]) * (1.0f / 1024.0f);
    __syncthreads();
    if (t == 0) {
        float m2[4], m1[2];
#pragma unroll
        for (int k = 0; k < 4; ++k) m2[k] = 0.5f * (sb[7 + 2 * k] + sb[8 + 2 * k]);
        m1[0] = 0.5f * (m2[0] + m2[1]);
        m1[1] = 0.5f * (m2[2] + m2[3]);
        sb[0] = 0.5f * (m1[0] + m1[1]);
        sb[1] = m1[0]; sb[2] = m1[1];
        sb[3] = m2[0]; sb[4] = m2[1]; sb[5] = m2[2]; sb[6] = m2[3];
    }
    __syncthreads();
    float rv[15];
#pragma unroll
    for (int k = 0; k < 15; ++k) rv[k] = sb[k];
    if (t < 15) {
        volatile float* sp = stats + (size_t)row * SSTR;   // write-through publish
        sp[t] = sb[t];
    }
    __syncthreads();
    if (t == 0) {
        __threadfence();                  // release: drain stores to device coherence point
        atomicAdd(counter, 1);
    }

    // ---- phase 2: write 4 target rows from registers ----
#pragma unroll
    for (int j = 0; j < 4; ++j) {
        f32x4* orow = out + ((size_t)(4 + j) * 1024 + row) * 2048;
        int sh = 3 - j;
#pragma unroll
        for (int i = 0; i < 8; ++i) {
            float v = rv[(1 << j) - 1 + (i >> sh)];
            f32x4 q = {v, v, v, v};
            orow[t + (i << 8)] = q;
        }
    }

    // ---- phase 3: wait for all rows' stats ----
    if (t == 0) {
        while (__hip_atomic_load(counter, __ATOMIC_RELAXED, __HIP_MEMORY_SCOPE_AGENT) < 1024) {
            __builtin_amdgcn_s_sleep(2);
        }
        __threadfence();                  // acquire: invalidate stale cache lines
    }
    __syncthreads();

    // ---- phase 4: BN scale/shift; wave j handles level j for this c ----
    __shared__ float ss[4][2];
    {
        int j = wave;
        volatile const float* sp = stats + (size_t)((lane << 4) + c) * SSTR;
        float sum = 0.f, sum2 = 0.f;
        if (j == 0) {
            float d = sp[0];
            sum = d; sum2 = d * d;
        } else {
            int base = (1 << j) - 1, pb = (1 << (j - 1)) - 1;
            for (int k = 0; k < (1 << j); ++k) {
                float d = sp[base + k] - sp[pb + (k >> 1)];
                sum += d; sum2 += d * d;
            }
        }
        float B = (float)(8192 >> j);
        sum *= B; sum2 *= B;
#pragma unroll
        for (int off = 32; off; off >>= 1) {
            sum  += __shfl_down(sum, off, 64);
            sum2 += __shfl_down(sum2, off, 64);
        }
        if (lane == 0) {
            const float N = 64.0f * 8192.0f;
            float mean = sum / N;
            float var = sum2 / N - mean * mean;
            float inv = rsqrtf(var + 1e-5f);
            float sc = gamma[(j << 4) + c] * inv;
            ss[j][0] = sc;
            ss[j][1] = beta[(j << 4) + c] - mean * sc;
        }
    }
    __syncthreads();

    // ---- phase 5: write 4 input rows ----
#pragma unroll
    for (int j = 0; j < 4; ++j) {
        float sc = ss[j][0], sh0 = ss[j][1];
        int shr = 3 - j;
        f32x4* orow = out + ((size_t)j * 1024 + row) * 2048;
#pragma unroll
        for (int i = 0; i < 8; ++i) {
            int run = i >> shr;           // uniform per i
            float mj = rv[(1 << j) - 1 + run];
            float d = (j == 0) ? mj : mj - rv[(1 << (j - 1)) - 1 + (run >> 1)];
            float v = d * sc + sh0;
            f32x4 q = {v, v, v, v};
            orow[t + (i << 8)] = q;
        }
    }
}

extern "C" void kernel_launch(void* const* d_in, const int* in_sizes, int n_in,
                              void* d_out, int out_size, void* d_ws, size_t ws_size,
                              hipStream_t stream) {
    const float* x     = (const float*)d_in[0];
    const float* gamma = (const float*)d_in[1];
    const float* beta  = (const float*)d_in[2];
    f32x4* out = (f32x4*)d_out;
    float* stats = (float*)d_ws;                       // 1024*16 f = 64 KiB
    int* counter = (int*)(stats + (size_t)1024 * SSTR);

    hipMemsetAsync(counter, 0, sizeof(int), stream);   // stream-ordered, capture-safe
    fused_kernel<<<1024, 256, 0, stream>>>(x, gamma, beta, stats, counter, out);
}

// Round 10
// 54.178 us; speedup vs baseline: 3.4834x; 3.4834x over previous
//
#include <hip/hip_runtime.h>

// x[64][16][8192] f32, J=4, LEVELS=13, eps 1e-5.
// targets[j] = blockmean(2^(13-j)); inputs[j] = BN(blockmean(2^(13-j)) - blockmean(2^(14-j))), input[0]=BN(m0)
// Output [2][4][64][16][8192] f32.
// K1 (= R5 kernel A): per row: NT-read row -> stats table + write 4 target rows (part=1).
// K2: 256 blocks, one per (j,b): bn coeffs for (j, all c), then ONE contiguous 512KB
//     linear store sweep (16 c x 8192), run-values hoisted to registers per channel.

#define SSTR 16
// stats row: [0]=m0, [1..2]=m1, [3..6]=m2, [7..14]=m3  (level j at base (1<<j)-1, count 1<<j)

typedef float f32x4 __attribute__((ext_vector_type(4)));

__global__ __launch_bounds__(256) void stats_targets_kernel(const float* __restrict__ x,
                                                            float* __restrict__ stats,
                                                            f32x4* __restrict__ out) {
    int row = blockIdx.x;                 // 0..1023  (b=row>>4, c=row&15)
    int t = threadIdx.x;                  // 0..255
    int lane = t & 63, wave = t >> 6;
    const f32x4* xr = reinterpret_cast<const f32x4*>(x) + (size_t)row * 2048;
    float s[8];
#pragma unroll
    for (int k = 0; k < 8; ++k) {
        f32x4 v = __builtin_nontemporal_load(&xr[t + 256 * k]);  // iter k = 1024-block k
        s[k] = (v.x + v.y) + (v.z + v.w);
    }
    __shared__ float red[8][4];
    __shared__ float sb[16];
#pragma unroll
    for (int k = 0; k < 8; ++k) {
        float v = s[k];
#pragma unroll
        for (int off = 32; off; off >>= 1) v += __shfl_down(v, off, 64);
        if (lane == 0) red[k][wave] = v;
    }
    __syncthreads();
    if (t < 8) sb[7 + t] = (red[t][0] + red[t][1] + red[t][2] + red[t][3]) * (1.0f / 1024.0f);
    __syncthreads();
    if (t == 0) {
        float m2[4], m1[2];
#pragma unroll
        for (int k = 0; k < 4; ++k) m2[k] = 0.5f * (sb[7 + 2 * k] + sb[8 + 2 * k]);
        m1[0] = 0.5f * (m2[0] + m2[1]);
        m1[1] = 0.5f * (m2[2] + m2[3]);
        sb[0] = 0.5f * (m1[0] + m1[1]);
        sb[1] = m1[0]; sb[2] = m1[1];
        sb[3] = m2[0]; sb[4] = m2[1]; sb[5] = m2[2]; sb[6] = m2[3];
    }
    __syncthreads();
    if (t < 15) stats[(size_t)row * SSTR + t] = sb[t];
    float rv[15];
#pragma unroll
    for (int k = 0; k < 15; ++k) rv[k] = sb[k];
#pragma unroll
    for (int j = 0; j < 4; ++j) {         // targets (part=1), 4 x 32KB rows
        f32x4* orow = out + ((size_t)(4 + j) * 1024 + row) * 2048;
        int sh = 3 - j;
#pragma unroll
        for (int i = 0; i < 8; ++i) {
            float v = rv[(1 << j) - 1 + (i >> sh)];
            f32x4 q = {v, v, v, v};
            orow[t + (i << 8)] = q;
        }
    }
}

template <int J>
__device__ inline void sweep_region(const float* __restrict__ val, f32x4* __restrict__ ob, int t) {
#pragma unroll
    for (int c = 0; c < 16; ++c) {
        float vv[8];
#pragma unroll
        for (int k = 0; k < 8; ++k) vv[k] = val[c * 8 + k];   // 2 x ds_read_b128, hoisted
#pragma unroll
        for (int k = 0; k < 8; ++k) {
            f32x4 q = {vv[k], vv[k], vv[k], vv[k]};
            ob[(c * 8 + k) * 256 + t] = q;                    // 512KB linear sweep
        }
    }
}

__global__ __launch_bounds__(256) void inputs_region_kernel(const float* __restrict__ stats,
                                                            const float* __restrict__ gamma,
                                                            const float* __restrict__ beta,
                                                            f32x4* __restrict__ out) {
    int blk = blockIdx.x;                 // 0..255 = [j][b]
    int j = blk >> 6;
    int b = blk & 63;
    int t = threadIdx.x;
    int lane = t & 63, wave = t >> 6;
    int nb = 1 << j;

    __shared__ float sc[16], sh[16];
    __shared__ float val[128];            // [c][k-step]: value for run (k >> (3-j))

    // bn coeffs for (j, all 16 c): wave w -> channels 4w..4w+3; lane = batch row
#pragma unroll
    for (int q = 0; q < 4; ++q) {
        int c = wave * 4 + q;
        const float* sp = stats + (size_t)((lane << 4) + c) * SSTR;
        float sum = 0.f, sum2 = 0.f;
        if (j == 0) {
            float d = sp[0];
            sum = d; sum2 = d * d;
        } else {
            int base = nb - 1, pb = (nb >> 1) - 1;
            for (int k = 0; k < nb; ++k) {
                float d = sp[base + k] - sp[pb + (k >> 1)];
                sum += d; sum2 += d * d;
            }
        }
        float B = (float)(8192 >> j);
        sum *= B; sum2 *= B;
#pragma unroll
        for (int off = 32; off; off >>= 1) {
            sum  += __shfl_down(sum, off, 64);
            sum2 += __shfl_down(sum2, off, 64);
        }
        if (lane == 0) {
            const float N = 64.0f * 8192.0f;
            float mean = sum / N;
            float var = sum2 / N - mean * mean;
            float s_ = gamma[(j << 4) + c] * rsqrtf(var + 1e-5f);
            sc[c] = s_;
            sh[c] = beta[(j << 4) + c] - mean * s_;
        }
    }
    __syncthreads();
    if (t < 128) {                        // fill run-value table for this (j,b)
        int c = t >> 3, k = t & 7;
        int run = k >> (3 - j);
        const float* sp = stats + (size_t)((b << 4) + c) * SSTR;
        float m = sp[nb - 1 + run];
        float d = (j == 0) ? m : m - sp[(nb >> 1) - 1 + (run >> 1)];
        val[t] = d * sc[c] + sh[c];
    }
    __syncthreads();

    f32x4* ob = out + ((size_t)j * 1024 + (size_t)b * 16) * 2048;  // contiguous 512KB
    switch (j) {
        case 0: sweep_region<0>(val, ob, t); break;
        case 1: sweep_region<1>(val, ob, t); break;
        case 2: sweep_region<2>(val, ob, t); break;
        default: sweep_region<3>(val, ob, t); break;
    }
}

extern "C" void kernel_launch(void* const* d_in, const int* in_sizes, int n_in,
                              void* d_out, int out_size, void* d_ws, size_t ws_size,
                              hipStream_t stream) {
    const float* x     = (const float*)d_in[0];
    const float* gamma = (const float*)d_in[1];
    const float* beta  = (const float*)d_in[2];
    f32x4* out = (f32x4*)d_out;
    float* stats = (float*)d_ws;          // 1024*16 f = 64 KiB

    stats_targets_kernel<<<1024, 256, 0, stream>>>(x, stats, out);
    inputs_region_kernel<<<256, 256, 0, stream>>>(stats, gamma, beta, out);
}